// Round 10
// baseline (195.162 us; speedup 1.0000x reference)
//
#include <hip/hip_runtime.h>
#include <hip/hip_bf16.h>

// SimpleRetention on MI355X — round 14.
// KP: fused prep — xpos table (f16 pairs, 2MB) + W transpose.  (frozen)
// K0: fused QKV gemm — r13 wave-split (distinct 64-col slice per wave). (frozen)
// K1: retention — r12 early-vb-pull body (correctness-verified) with PLAIN
//     __launch_bounds__(256): r12's regression was the (256,2) attribute's
//     128-VGPR cap spilling qf+vb+acc (WRITE_SIZE 33->50MB); LDS caps us at
//     2 blocks/CU anyway so VGPR<=256 is free. vb pulled under QK; both
//     next-tile stages issue after one lgkm-only barrier, covered by PV;
//     2 barriers/iter.

#define S_LEN 2048
#define HD 256
#define BN 16

typedef _Float16 half8 __attribute__((ext_vector_type(8)));
typedef _Float16 half4 __attribute__((ext_vector_type(4)));
typedef _Float16 half2v __attribute__((ext_vector_type(2)));
typedef float floatx16 __attribute__((ext_vector_type(16)));

__device__ __forceinline__ void gl_lds16(const void* g, void* l) {
  __builtin_amdgcn_global_load_lds(
      (const __attribute__((address_space(1))) unsigned int*)(unsigned long long)g,
      (__attribute__((address_space(3))) unsigned int*)(unsigned int)(unsigned long long)l,
      16, 0, 0);
}

// ---------------- Kernel P: xpos table (f16) + W transpose ----------------
__global__ __launch_bounds__(256) void prep_kernel(
    const float* __restrict__ WQ, const float* __restrict__ WK,
    const float* __restrict__ WV, _Float16* __restrict__ WT,
    _Float16* __restrict__ TBL) {
  const int b = blockIdx.x;
  const int tid = threadIdx.x;
  if (b < 1024) {
    const int idx = b * 256 + tid;  // 0..262143 = pos*128 + i2
    const int i2 = idx & 127;
    const int pos = idx >> 7;
    float inv_freq = exp2f(-(float)i2 * (13.287712379549449f / 128.0f));
    float lbase = log2f(((float)(2 * i2) + 102.4f) / 358.4f);
    float ang = (float)pos * inv_freq;
    float sn, cs;
    sincosf(ang, &sn, &cs);
    float scl = exp2f((float)pos * (1.0f / 512.0f) * lbase);  // Q: *scale
    float rscl = 1.0f / scl;                                  // K: /scale
    half2v tq, tk;
    tq[0] = (_Float16)(cs * scl);  tq[1] = (_Float16)(sn * scl);
    tk[0] = (_Float16)(cs * rscl); tk[1] = (_Float16)(sn * rscl);
    *(half2v*)&TBL[(long)idx * 2] = tq;
    *(half2v*)&TBL[(long)(262144 + idx) * 2] = tk;
    return;
  }
  __shared__ _Float16 trans[64][72];
  const int bb = b - 1024;          // 0..47
  const int w = bb >> 4;
  const int tk = ((bb & 15) & 3) * 64;
  const int tn = ((bb & 15) >> 2) * 64;
  const float* W = (w == 0) ? WQ : (w == 1) ? WK : WV;
#pragma unroll
  for (int u = 0; u < 4; ++u) {
    int idx = u * 256 + tid;
    int k = idx >> 4;
    int nq = (idx & 15) * 4;
    float4 v = *(const float4*)&W[(tk + k) * HD + tn + nq];
    trans[nq + 0][k] = (_Float16)v.x;
    trans[nq + 1][k] = (_Float16)v.y;
    trans[nq + 2][k] = (_Float16)v.z;
    trans[nq + 3][k] = (_Float16)v.w;
  }
  __syncthreads();
#pragma unroll
  for (int u = 0; u < 2; ++u) {
    int idx = u * 256 + tid;
    int n = idx >> 3;
    int kq = (idx & 7) * 8;
    *(uint4*)&WT[((long)w * HD + tn + n) * HD + tk + kq] = *(const uint4*)&trans[n][kq];
  }
}

// ---------------- Kernel 0: fused QKV projection + xpos ----------------
__global__ __launch_bounds__(256) void gemm_qkv_kernel(
    const float* __restrict__ X, const _Float16* __restrict__ WT,
    const _Float16* __restrict__ TBL,
    _Float16* __restrict__ Q, _Float16* __restrict__ K,
    _Float16* __restrict__ VT) {
  __shared__ __align__(16) unsigned char smem[66560];
  unsigned char* ep = smem + 32768;

  const int tid = threadIdx.x;
  const int lane = tid & 63;
  const int w = tid >> 6;
  const int l31 = lane & 31;
  const int lh = lane >> 5;
  const int m0 = blockIdx.x * 64;

  // stage X (64 rows x 256 fp32) -> f16 swizzled: chunk p = c ^ (row&31)
#pragma unroll
  for (int i = 0; i < 8; ++i) {
    int id = i * 256 + tid;
    int row = id >> 5, c = id & 31;
    int p = c ^ (row & 31);
    const float4* s = (const float4*)&X[(long)(m0 + row) * HD + c * 8];
    float4 v0 = s[0], v1 = s[1];
    half8 h;
    h[0] = (_Float16)v0.x; h[1] = (_Float16)v0.y;
    h[2] = (_Float16)v0.z; h[3] = (_Float16)v0.w;
    h[4] = (_Float16)v1.x; h[5] = (_Float16)v1.y;
    h[6] = (_Float16)v1.z; h[7] = (_Float16)v1.w;
    *(half8*)(smem + row * 512 + p * 16) = h;
  }
  __syncthreads();

  const int bn = m0 >> 11;
  const int srow0 = m0 & (S_LEN - 1);
  const int ncol0 = w * 64;  // this wave's 64-col slice

  for (int wsel = 0; wsel < 3; ++wsel) {
    const _Float16* Wb = WT + (long)wsel * HD * HD;
    floatx16 acc[2][2];  // [mtile][nt]
#pragma unroll
    for (int mt = 0; mt < 2; ++mt)
#pragma unroll
      for (int nt = 0; nt < 2; ++nt)
#pragma unroll
        for (int e = 0; e < 16; ++e) acc[mt][nt][e] = 0.f;

    // depth-5 register ring over this wave's 2 distinct n-tiles
    half8 b[5][2];
#pragma unroll
    for (int pk = 0; pk < 5; ++pk)
#pragma unroll
      for (int nt = 0; nt < 2; ++nt)
        b[pk][nt] = *(const half8*)(Wb + (long)(ncol0 + nt * 32 + l31) * HD +
                                    pk * 16 + lh * 8);
#pragma unroll
    for (int ks16 = 0; ks16 < 16; ++ks16) {
      const int slot = ks16 % 5;
      int p = (ks16 * 2 + lh) ^ l31;  // row&31 == l31 for both mtiles
      half8 af0 = *(const half8*)(smem + l31 * 512 + p * 16);
      half8 af1 = *(const half8*)(smem + (32 + l31) * 512 + p * 16);
#pragma unroll
      for (int nt = 0; nt < 2; ++nt) {
        acc[0][nt] = __builtin_amdgcn_mfma_f32_32x32x16_f16(af0, b[slot][nt], acc[0][nt], 0, 0, 0);
        acc[1][nt] = __builtin_amdgcn_mfma_f32_32x32x16_f16(af1, b[slot][nt], acc[1][nt], 0, 0, 0);
      }
      if (ks16 + 5 < 16) {
#pragma unroll
        for (int nt = 0; nt < 2; ++nt)
          b[slot][nt] = *(const half8*)(Wb + (long)(ncol0 + nt * 32 + l31) * HD +
                                        (ks16 + 5) * 16 + lh * 8);
      }
    }

    if (wsel < 2) {
      // (1) dump C-fragments to ep as f16
#pragma unroll
      for (int mt = 0; mt < 2; ++mt)
#pragma unroll
        for (int nt = 0; nt < 2; ++nt) {
          int col = ncol0 + nt * 32 + l31;
#pragma unroll
          for (int reg = 0; reg < 16; ++reg) {
            int rmap = (reg & 3) + 8 * (reg >> 2) + 4 * lh;
            *(_Float16*)(ep + (mt * 32 + rmap) * 528 + col * 2) =
                (_Float16)acc[mt][nt][reg];
          }
        }
      __syncthreads();
      // (2) row-packed re-read, f16-table xpos (pairs in-lane), uint4 out
      _Float16* o = wsel ? K : Q;
      const _Float16* tb_base = TBL + (long)wsel * 2048 * 128 * 2;
#pragma unroll
      for (int u = 0; u < 8; ++u) {
        int id = u * 256 + tid;
        int row = id >> 5;
        int cq = (id & 31) * 8;
        half8 x = *(const half8*)(ep + row * 528 + cq * 2);
        half8 t = *(const half8*)&tb_base[((long)(srow0 + row) * 128 + (cq >> 1)) * 2];
        half8 y;
        y[0] = x[0] * t[0] - x[1] * t[1];
        y[1] = x[1] * t[0] + x[0] * t[1];
        y[2] = x[2] * t[2] - x[3] * t[3];
        y[3] = x[3] * t[2] + x[2] * t[3];
        y[4] = x[4] * t[4] - x[5] * t[5];
        y[5] = x[5] * t[4] + x[4] * t[5];
        y[6] = x[6] * t[6] - x[7] * t[7];
        y[7] = x[7] * t[6] + x[6] * t[7];
        *(half8*)&o[(long)(m0 + row) * HD + cq] = y;
      }
      __syncthreads();
    } else {
      // V: transpose through LDS -> VT[bn][h][s]
      __syncthreads();  // all waves done reading xs
      _Float16 (*vt)[72] = (_Float16(*)[72])smem;
#pragma unroll
      for (int mt = 0; mt < 2; ++mt)
#pragma unroll
        for (int nt = 0; nt < 2; ++nt) {
          int h = ncol0 + nt * 32 + l31;
#pragma unroll
          for (int reg = 0; reg < 16; ++reg) {
            int rmap = (reg & 3) + 8 * (reg >> 2) + 4 * lh;
            vt[h][mt * 32 + rmap] = (_Float16)acc[mt][nt][reg];
          }
        }
      __syncthreads();
#pragma unroll
      for (int u = 0; u < 8; ++u) {
        int id = u * 256 + tid;
        int h = id >> 3, sj = (id & 7) * 8;
        *(uint4*)&VT[((long)bn * HD + h) * S_LEN + srow0 + sj] = *(const uint4*)&vt[h][sj];
      }
    }
  }
}

// ---------------- Kernel 1: retention — early vb pull, 2 barriers ----------
__global__ __launch_bounds__(256) void retention_kernel(
    const _Float16* __restrict__ Q, const _Float16* __restrict__ K,
    const _Float16* __restrict__ VT, float* __restrict__ out) {
  // ksb 32KB + vsb 32KB + sc 9KB = 73KB -> 2 blocks/CU (LDS-capped).
  // NOTE: plain __launch_bounds__(256) — NO min-waves arg. r12's regression
  // was the (256,2) 128-VGPR cap spilling qf+vb+acc to scratch.
  __shared__ __align__(16) unsigned char smem[74752];
  unsigned char* ksb = smem;            // 64 t-rows x 512B, p = c ^ (t&31)
  unsigned char* vsb = smem + 32768;    // 256 h-rows x 128B, p = c ^ (h&7)
  _Float16 (*sc)[72] = (_Float16(*)[72])(smem + 65536);  // S[q][t]

  const int tid = threadIdx.x;
  const int lane = tid & 63;
  const int w = tid >> 6;
  const int l31 = lane & 31;
  const int lh = lane >> 5;
  const int qtile = w >> 1;  // q-half for QK-B / PV-A / output rows
  const int ttile = w & 1;   // t-half for QK-A
  const int hhalf = w & 1;   // h-half for PV-B

  // Complementary pairing: CU pair (L, L+256) sums to exactly 33 iterations.
  const int L = blockIdx.x;
  const int head = L & 15;
  const int g4 = L >> 4;  // 0..31
  const int qt = (g4 < 16) ? (31 - g4) : (g4 - 16);
  const int q0 = qt * 64;

  const _Float16* Qh = Q + (long)head * S_LEN * HD;
  const _Float16* Kh = K + (long)head * S_LEN * HD;
  const _Float16* VTh = VT + (long)head * HD * S_LEN;

  // Q register-resident as B-frags
  half8 qf[16];
  {
    const _Float16* qrow = Qh + (long)(q0 + qtile * 32 + l31) * HD + lh * 8;
#pragma unroll
    for (int ks16 = 0; ks16 < 16; ++ks16)
      qf[ks16] = *(const half8*)(qrow + ks16 * 16);
  }

  floatx16 acc[4];
#pragma unroll
  for (int nt = 0; nt < 4; ++nt)
#pragma unroll
    for (int e = 0; e < 16; ++e) acc[nt][e] = 0.f;

  const float LG = -0.0458036896f;  // log2(0.96875)
  float Cg[16];
#pragma unroll
  for (int g = 0; g < 4; ++g)
#pragma unroll
    for (int r = 0; r < 4; ++r) Cg[4 * g + r] = exp2f(-(float)(8 * g + r) * LG);

#define STAGE_K(T0)                                                        \
  {                                                                        \
    _Pragma("unroll") for (int jj = 0; jj < 8; ++jj) {                     \
      int li = w * 8 + jj;                                                 \
      int row = li * 2 + lh;                                               \
      int c = l31 ^ (row & 31);                                            \
      gl_lds16(Kh + (long)((T0) + row) * HD + c * 8, ksb + li * 1024);     \
    }                                                                      \
  }
#define STAGE_V(T0)                                                        \
  {                                                                        \
    _Pragma("unroll") for (int jj = 0; jj < 8; ++jj) {                     \
      int li = w * 8 + jj;                                                 \
      int row = li * 8 + (lane >> 3);                                      \
      int c = (lane & 7) ^ (row & 7);                                      \
      gl_lds16(VTh + (long)row * S_LEN + (T0) + c * 8, vsb + li * 1024);   \
    }                                                                      \
  }

  // prologue: stage tile 0
  STAGE_K(0);
  STAGE_V(0);

  for (int kt = 0; kt <= qt; ++kt) {
    const int t0 = kt * 64;
    // B1: staging landed (explicit vmcnt drain, cross-wave LDS visibility)
    asm volatile("s_waitcnt vmcnt(0)" ::: "memory");
    __syncthreads();

    // S^T = K * Q^T  (m = t, n = q)
    floatx16 s;
#pragma unroll
    for (int e = 0; e < 16; ++e) s[e] = 0.f;
    {
      const unsigned char* kbase = ksb + (ttile * 32 + l31) * 512;
#pragma unroll
      for (int ks16 = 0; ks16 < 16; ++ks16) {
        int p = (ks16 * 2 + lh) ^ l31;
        half8 a = *(const half8*)(kbase + p * 16);
        s = __builtin_amdgcn_mfma_f32_32x32x16_f16(a, qf[ks16], s, 0, 0, 0);
      }
    }

    // pull V B-frags vsb -> regs (LDS reads; hidden under QK's MFMA stream)
    half8 vb[4][4];
#pragma unroll
    for (int kst = 0; kst < 4; ++kst)
#pragma unroll
      for (int nt = 0; nt < 4; ++nt) {
        int h = hhalf * 128 + nt * 32 + l31;
        int p = (kst * 2 + lh) ^ (h & 7);
        vb[kst][nt] = *(const half8*)(vsb + h * 128 + p * 16);
      }

    // decay + causal mask (1 exp2 + 16 fmul), b64-packed sc writes
    {
      const int qg = q0 + qtile * 32 + l31;
      const int tb = t0 + ttile * 32 + 4 * lh;
      const int dd = qg - tb;
      const float E = exp2f((float)dd * LG);
#pragma unroll
      for (int g = 0; g < 4; ++g) {
        half4 h4;
#pragma unroll
        for (int r = 0; r < 4; ++r) {
          int o = 8 * g + r;
          float wv = (dd >= o) ? E * Cg[4 * g + r] : 0.f;
          h4[r] = (_Float16)(s[4 * g + r] * wv);
        }
        *(half4*)&sc[qtile * 32 + l31][ttile * 32 + 4 * lh + 8 * g] = h4;
      }
    }

    // B2: lgkm-only barrier — sc visible, ALL ksb/vsb reads complete
    // block-wide; vmcnt queue untouched. Safe to overwrite ksb/vsb now.
    asm volatile("s_waitcnt lgkmcnt(0)" ::: "memory");
    __builtin_amdgcn_s_barrier();
    __builtin_amdgcn_sched_barrier(0);

    // stage NEXT tile into the same buffers — covered by the whole PV phase
    if (kt < qt) {
      STAGE_K(t0 + 64);
      STAGE_V(t0 + 64);
    }

    // PV: acc[q][h] += S[q][t] * V[t][h]; B from registers (vb)
#pragma unroll
    for (int kst = 0; kst < 4; ++kst) {
      half8 a = *(const half8*)&sc[qtile * 32 + l31][kst * 16 + lh * 8];
#pragma unroll
      for (int nt = 0; nt < 4; ++nt)
        acc[nt] = __builtin_amdgcn_mfma_f32_32x32x16_f16(a, vb[kst][nt], acc[nt], 0, 0, 0);
    }
  }

  // epilogue: C-layout fp32 stores
  const long rbase = (long)head * S_LEN + q0 + qtile * 32;
#pragma unroll
  for (int nt = 0; nt < 4; ++nt) {
    int col = hhalf * 128 + nt * 32 + l31;
#pragma unroll
    for (int reg = 0; reg < 16; ++reg) {
      int rmap = (reg & 3) + 8 * (reg >> 2) + 4 * lh;
      out[(rbase + rmap) * HD + col] = acc[nt][reg];
    }
  }
}

extern "C" void kernel_launch(void* const* d_in, const int* in_sizes, int n_in,
                              void* d_out, int out_size, void* d_ws, size_t ws_size,
                              hipStream_t stream) {
  const float* X  = (const float*)d_in[0];
  const float* WQ = (const float*)d_in[1];
  const float* WK = (const float*)d_in[2];
  const float* WV = (const float*)d_in[3];
  float* out = (float*)d_out;

  _Float16* Qh = (_Float16*)d_ws;
  _Float16* Kh = Qh + (size_t)BN * S_LEN * HD;
  _Float16* VTh = Kh + (size_t)BN * S_LEN * HD;
  _Float16* WT = VTh + (size_t)BN * S_LEN * HD;
  _Float16* TBL = WT + (size_t)3 * HD * HD;  // 2MB f16 xpos table

  prep_kernel<<<dim3(1072), dim3(256), 0, stream>>>(WQ, WK, WV, WT, TBL);
  gemm_qkv_kernel<<<dim3((BN * S_LEN) / 64), dim3(256), 0, stream>>>(
      X, WT, TBL, Qh, Kh, VTh);
  retention_kernel<<<dim3(512), dim3(256), 0, stream>>>(Qh, Kh, VTh, out);
}

// Round 11
// 173.360 us; speedup vs baseline: 1.1258x; 1.1258x over previous
//
#include <hip/hip_runtime.h>
#include <hip/hip_bf16.h>

// SimpleRetention on MI355X — round 15.
// KP: fused prep — xpos table (f16 pairs, 2MB) + W transpose.  (frozen)
// K0: fused QKV gemm — NEW: 512 threads/block, 8 waves x 32-col slices at the
//     same 64-row tile / grid / traffic -> 4 waves/SIMD (was 2). The gemm is
//     latency-stall-bound; this doubles TLP without adding B-traffic.
// K1: retention — r13 byte-exact body (verified 70.6/71.1us twice), FROZEN:
//     vb inline in PV, 3 barriers, K-prefetch under PV, complementary pairing.
//     Three V-path restructures (r3, r7/r8, r14) all regressed — no more.

#define S_LEN 2048
#define HD 256
#define BN 16

typedef _Float16 half8 __attribute__((ext_vector_type(8)));
typedef _Float16 half4 __attribute__((ext_vector_type(4)));
typedef _Float16 half2v __attribute__((ext_vector_type(2)));
typedef float floatx16 __attribute__((ext_vector_type(16)));

__device__ __forceinline__ void gl_lds16(const void* g, void* l) {
  __builtin_amdgcn_global_load_lds(
      (const __attribute__((address_space(1))) unsigned int*)(unsigned long long)g,
      (__attribute__((address_space(3))) unsigned int*)(unsigned int)(unsigned long long)l,
      16, 0, 0);
}

// ---------------- Kernel P: xpos table (f16) + W transpose ----------------
__global__ __launch_bounds__(256) void prep_kernel(
    const float* __restrict__ WQ, const float* __restrict__ WK,
    const float* __restrict__ WV, _Float16* __restrict__ WT,
    _Float16* __restrict__ TBL) {
  const int b = blockIdx.x;
  const int tid = threadIdx.x;
  if (b < 1024) {
    const int idx = b * 256 + tid;  // 0..262143 = pos*128 + i2
    const int i2 = idx & 127;
    const int pos = idx >> 7;
    float inv_freq = exp2f(-(float)i2 * (13.287712379549449f / 128.0f));
    float lbase = log2f(((float)(2 * i2) + 102.4f) / 358.4f);
    float ang = (float)pos * inv_freq;
    float sn, cs;
    sincosf(ang, &sn, &cs);
    float scl = exp2f((float)pos * (1.0f / 512.0f) * lbase);  // Q: *scale
    float rscl = 1.0f / scl;                                  // K: /scale
    half2v tq, tk;
    tq[0] = (_Float16)(cs * scl);  tq[1] = (_Float16)(sn * scl);
    tk[0] = (_Float16)(cs * rscl); tk[1] = (_Float16)(sn * rscl);
    *(half2v*)&TBL[(long)idx * 2] = tq;
    *(half2v*)&TBL[(long)(262144 + idx) * 2] = tk;
    return;
  }
  __shared__ _Float16 trans[64][72];
  const int bb = b - 1024;          // 0..47
  const int w = bb >> 4;
  const int tk = ((bb & 15) & 3) * 64;
  const int tn = ((bb & 15) >> 2) * 64;
  const float* W = (w == 0) ? WQ : (w == 1) ? WK : WV;
#pragma unroll
  for (int u = 0; u < 4; ++u) {
    int idx = u * 256 + tid;
    int k = idx >> 4;
    int nq = (idx & 15) * 4;
    float4 v = *(const float4*)&W[(tk + k) * HD + tn + nq];
    trans[nq + 0][k] = (_Float16)v.x;
    trans[nq + 1][k] = (_Float16)v.y;
    trans[nq + 2][k] = (_Float16)v.z;
    trans[nq + 3][k] = (_Float16)v.w;
  }
  __syncthreads();
#pragma unroll
  for (int u = 0; u < 2; ++u) {
    int idx = u * 256 + tid;
    int n = idx >> 3;
    int kq = (idx & 7) * 8;
    *(uint4*)&WT[((long)w * HD + tn + n) * HD + tk + kq] = *(const uint4*)&trans[n][kq];
  }
}

// ---------------- Kernel 0: fused QKV projection + xpos (8 waves) ----------
__global__ __launch_bounds__(512) void gemm_qkv_kernel(
    const float* __restrict__ X, const _Float16* __restrict__ WT,
    const _Float16* __restrict__ TBL,
    _Float16* __restrict__ Q, _Float16* __restrict__ K,
    _Float16* __restrict__ VT) {
  // xs 32KB + ep 33KB = 65KB -> 2 blocks/CU (130KB), 16 waves/CU = 4/SIMD.
  __shared__ __align__(16) unsigned char smem[66560];
  unsigned char* ep = smem + 32768;

  const int tid = threadIdx.x;
  const int lane = tid & 63;
  const int w = tid >> 6;        // 0..7
  const int l31 = lane & 31;
  const int lh = lane >> 5;
  const int m0 = blockIdx.x * 64;

  // stage X (64 rows x 256 fp32) -> f16 swizzled: chunk p = c ^ (row&31)
#pragma unroll
  for (int i = 0; i < 4; ++i) {
    int id = i * 512 + tid;
    int row = id >> 5, c = id & 31;
    int p = c ^ (row & 31);
    const float4* s = (const float4*)&X[(long)(m0 + row) * HD + c * 8];
    float4 v0 = s[0], v1 = s[1];
    half8 h;
    h[0] = (_Float16)v0.x; h[1] = (_Float16)v0.y;
    h[2] = (_Float16)v0.z; h[3] = (_Float16)v0.w;
    h[4] = (_Float16)v1.x; h[5] = (_Float16)v1.y;
    h[6] = (_Float16)v1.z; h[7] = (_Float16)v1.w;
    *(half8*)(smem + row * 512 + p * 16) = h;
  }
  __syncthreads();

  const int bn = m0 >> 11;
  const int srow0 = m0 & (S_LEN - 1);
  const int ncol0 = w * 32;  // this wave's 32-col slice

  for (int wsel = 0; wsel < 3; ++wsel) {
    const _Float16* Wb = WT + (long)wsel * HD * HD;
    floatx16 acc[2];  // [mtile]
#pragma unroll
    for (int mt = 0; mt < 2; ++mt)
#pragma unroll
      for (int e = 0; e < 16; ++e) acc[mt][e] = 0.f;

    // depth-5 register ring over this wave's single 32-col n-tile
    half8 b[5];
#pragma unroll
    for (int pk = 0; pk < 5; ++pk)
      b[pk] = *(const half8*)(Wb + (long)(ncol0 + l31) * HD + pk * 16 + lh * 8);
#pragma unroll
    for (int ks16 = 0; ks16 < 16; ++ks16) {
      const int slot = ks16 % 5;
      int p = (ks16 * 2 + lh) ^ l31;  // row&31 == l31 for both mtiles
      half8 af0 = *(const half8*)(smem + l31 * 512 + p * 16);
      half8 af1 = *(const half8*)(smem + (32 + l31) * 512 + p * 16);
      acc[0] = __builtin_amdgcn_mfma_f32_32x32x16_f16(af0, b[slot], acc[0], 0, 0, 0);
      acc[1] = __builtin_amdgcn_mfma_f32_32x32x16_f16(af1, b[slot], acc[1], 0, 0, 0);
      if (ks16 + 5 < 16)
        b[slot] = *(const half8*)(Wb + (long)(ncol0 + l31) * HD +
                                  (ks16 + 5) * 16 + lh * 8);
    }

    if (wsel < 2) {
      // (1) dump C-fragments to ep as f16
      const int col = ncol0 + l31;
#pragma unroll
      for (int mt = 0; mt < 2; ++mt)
#pragma unroll
        for (int reg = 0; reg < 16; ++reg) {
          int rmap = (reg & 3) + 8 * (reg >> 2) + 4 * lh;
          *(_Float16*)(ep + (mt * 32 + rmap) * 528 + col * 2) =
              (_Float16)acc[mt][reg];
        }
      __syncthreads();
      // (2) row-packed re-read, f16-table xpos (pairs in-lane), uint4 out
      _Float16* o = wsel ? K : Q;
      const _Float16* tb_base = TBL + (long)wsel * 2048 * 128 * 2;
#pragma unroll
      for (int u = 0; u < 4; ++u) {
        int id = u * 512 + tid;
        int row = id >> 5;
        int cq = (id & 31) * 8;
        half8 x = *(const half8*)(ep + row * 528 + cq * 2);
        half8 t = *(const half8*)&tb_base[((long)(srow0 + row) * 128 + (cq >> 1)) * 2];
        half8 y;
        y[0] = x[0] * t[0] - x[1] * t[1];
        y[1] = x[1] * t[0] + x[0] * t[1];
        y[2] = x[2] * t[2] - x[3] * t[3];
        y[3] = x[3] * t[2] + x[2] * t[3];
        y[4] = x[4] * t[4] - x[5] * t[5];
        y[5] = x[5] * t[4] + x[4] * t[5];
        y[6] = x[6] * t[6] - x[7] * t[7];
        y[7] = x[7] * t[6] + x[6] * t[7];
        *(half8*)&o[(long)(m0 + row) * HD + cq] = y;
      }
      __syncthreads();
    } else {
      // V: transpose through LDS -> VT[bn][h][s]
      __syncthreads();  // all waves done reading xs
      _Float16 (*vt)[72] = (_Float16(*)[72])smem;
      const int h = ncol0 + l31;
#pragma unroll
      for (int mt = 0; mt < 2; ++mt)
#pragma unroll
        for (int reg = 0; reg < 16; ++reg) {
          int rmap = (reg & 3) + 8 * (reg >> 2) + 4 * lh;
          vt[h][mt * 32 + rmap] = (_Float16)acc[mt][reg];
        }
      __syncthreads();
#pragma unroll
      for (int u = 0; u < 4; ++u) {
        int id = u * 512 + tid;
        int hh = id >> 3, sj = (id & 7) * 8;
        *(uint4*)&VT[((long)bn * HD + hh) * S_LEN + srow0 + sj] = *(const uint4*)&vt[hh][sj];
      }
    }
  }
}

// ---------------- Kernel 1: retention, TK=64, prefetched staging (FROZEN) --
__global__ __launch_bounds__(256) void retention_kernel(
    const _Float16* __restrict__ Q, const _Float16* __restrict__ K,
    const _Float16* __restrict__ VT, float* __restrict__ out) {
  // ksb 32KB + vsb 32KB + sc 9KB (de-aliased) = 73KB -> 2 blocks/CU
  __shared__ __align__(16) unsigned char smem[74752];
  unsigned char* ksb = smem;            // 64 t-rows x 512B, p = c ^ (t&31)
  unsigned char* vsb = smem + 32768;    // 256 h-rows x 128B, p = c ^ (h&7)
  _Float16 (*sc)[72] = (_Float16(*)[72])(smem + 65536);  // S[q][t], own buffer

  const int tid = threadIdx.x;
  const int lane = tid & 63;
  const int w = tid >> 6;
  const int l31 = lane & 31;
  const int lh = lane >> 5;
  const int qtile = w >> 1;  // q-half for QK-B / PV-A / output rows
  const int ttile = w & 1;   // t-half for QK-A
  const int hhalf = w & 1;   // h-half for PV-B

  // Complementary pairing: co-resident CU pair is (L, L+256) under
  // round-robin XCD dispatch; qt(L)+qt(L+256)=31.
  const int L = blockIdx.x;
  const int head = L & 15;
  const int g4 = L >> 4;  // 0..31
  const int qt = (g4 < 16) ? (31 - g4) : (g4 - 16);
  const int q0 = qt * 64;

  const _Float16* Qh = Q + (long)head * S_LEN * HD;
  const _Float16* Kh = K + (long)head * S_LEN * HD;
  const _Float16* VTh = VT + (long)head * HD * S_LEN;

  // Q register-resident as B-frags: n = q-row, k = ks*16 + lh*8 + j
  half8 qf[16];
  {
    const _Float16* qrow = Qh + (long)(q0 + qtile * 32 + l31) * HD + lh * 8;
#pragma unroll
    for (int ks16 = 0; ks16 < 16; ++ks16)
      qf[ks16] = *(const half8*)(qrow + ks16 * 16);
  }

  floatx16 acc[4];
#pragma unroll
  for (int nt = 0; nt < 4; ++nt)
#pragma unroll
    for (int e = 0; e < 16; ++e) acc[nt][e] = 0.f;

  const float LG = -0.0458036896f;  // log2(0.96875)
  float Cg[16];
#pragma unroll
  for (int g = 0; g < 4; ++g)
#pragma unroll
    for (int r = 0; r < 4; ++r) Cg[4 * g + r] = exp2f(-(float)(8 * g + r) * LG);

#define STAGE_K(T0)                                                        \
  {                                                                        \
    _Pragma("unroll") for (int j = 0; j < 8; ++j) {                        \
      int li = w * 8 + j;                                                  \
      int row = li * 2 + lh;                                               \
      int c = l31 ^ (row & 31);                                            \
      gl_lds16(Kh + (long)((T0) + row) * HD + c * 8, ksb + li * 1024);     \
    }                                                                      \
  }
#define STAGE_V(T0)                                                        \
  {                                                                        \
    _Pragma("unroll") for (int j = 0; j < 8; ++j) {                        \
      int li = w * 8 + j;                                                  \
      int row = li * 8 + (lane >> 3);                                      \
      int c = (lane & 7) ^ (row & 7);                                      \
      gl_lds16(VTh + (long)row * S_LEN + (T0) + c * 8, vsb + li * 1024);   \
    }                                                                      \
  }

  // prologue: stage tile 0
  STAGE_K(0);
  STAGE_V(0);

  for (int kt = 0; kt <= qt; ++kt) {
    const int t0 = kt * 64;
    // B1: staging complete. Explicit vmcnt drain (cross-wave visibility).
    asm volatile("s_waitcnt vmcnt(0)" ::: "memory");
    __syncthreads();

    // S^T = K * Q^T  (m = t, n = q) -> decay applies in C-layout
    floatx16 s;
#pragma unroll
    for (int e = 0; e < 16; ++e) s[e] = 0.f;
    {
      const unsigned char* kbase = ksb + (ttile * 32 + l31) * 512;
#pragma unroll
      for (int ks16 = 0; ks16 < 16; ++ks16) {
        int p = (ks16 * 2 + lh) ^ l31;
        half8 a = *(const half8*)(kbase + p * 16);
        s = __builtin_amdgcn_mfma_f32_32x32x16_f16(a, qf[ks16], s, 0, 0, 0);
      }
    }

    // decay + causal mask (factorized: 1 exp2 + 16 fmul), b64-packed sc writes
    {
      const int qg = q0 + qtile * 32 + l31;
      const int tb = t0 + ttile * 32 + 4 * lh;
      const int dd = qg - tb;
      const float E = exp2f((float)dd * LG);  // gamma^(qg-tb)
#pragma unroll
      for (int g = 0; g < 4; ++g) {
        half4 h4;
#pragma unroll
        for (int r = 0; r < 4; ++r) {
          int o = 8 * g + r;
          float wv = (dd >= o) ? E * Cg[4 * g + r] : 0.f;
          h4[r] = (_Float16)(s[4 * g + r] * wv);
        }
        *(half4*)&sc[qtile * 32 + l31][ttile * 32 + 4 * lh + 8 * g] = h4;
      }
    }
    __syncthreads();  // B3: sc ready; all ksb reads complete

    // prefetch next K tile now -> latency hides under PV, lands at B4 drain
    if (kt < qt) STAGE_K(t0 + 64);

    // PV: acc[q][h] += S[q][t] * V[t][h]  (vb reads INLINE — r8 lesson)
#pragma unroll
    for (int kst = 0; kst < 4; ++kst) {
      half8 a = *(const half8*)&sc[qtile * 32 + l31][kst * 16 + lh * 8];
#pragma unroll
      for (int nt = 0; nt < 4; ++nt) {
        int h = hhalf * 128 + nt * 32 + l31;
        int p = (kst * 2 + lh) ^ (h & 7);
        half8 b = *(const half8*)(vsb + h * 128 + p * 16);
        acc[nt] = __builtin_amdgcn_mfma_f32_32x32x16_f16(a, b, acc[nt], 0, 0, 0);
      }
    }
    // B4: sc/vsb reads done; prefetched K landed (explicit drain)
    asm volatile("s_waitcnt vmcnt(0)" ::: "memory");
    __syncthreads();

    if (kt < qt) STAGE_V(t0 + 64);  // drains at next B1
  }

  // epilogue: C-layout fp32 stores
  const long rbase = (long)head * S_LEN + q0 + qtile * 32;
#pragma unroll
  for (int nt = 0; nt < 4; ++nt) {
    int col = hhalf * 128 + nt * 32 + l31;
#pragma unroll
    for (int reg = 0; reg < 16; ++reg) {
      int rmap = (reg & 3) + 8 * (reg >> 2) + 4 * lh;
      out[(rbase + rmap) * HD + col] = acc[nt][reg];
    }
  }
}

extern "C" void kernel_launch(void* const* d_in, const int* in_sizes, int n_in,
                              void* d_out, int out_size, void* d_ws, size_t ws_size,
                              hipStream_t stream) {
  const float* X  = (const float*)d_in[0];
  const float* WQ = (const float*)d_in[1];
  const float* WK = (const float*)d_in[2];
  const float* WV = (const float*)d_in[3];
  float* out = (float*)d_out;

  _Float16* Qh = (_Float16*)d_ws;
  _Float16* Kh = Qh + (size_t)BN * S_LEN * HD;
  _Float16* VTh = Kh + (size_t)BN * S_LEN * HD;
  _Float16* WT = VTh + (size_t)BN * S_LEN * HD;
  _Float16* TBL = WT + (size_t)3 * HD * HD;  // 2MB f16 xpos table

  prep_kernel<<<dim3(1072), dim3(256), 0, stream>>>(WQ, WK, WV, WT, TBL);
  gemm_qkv_kernel<<<dim3((BN * S_LEN) / 64), dim3(512), 0, stream>>>(
      X, WT, TBL, Qh, Kh, VTh);
  retention_kernel<<<dim3(512), dim3(256), 0, stream>>>(Qh, Kh, VTh, out);
}